// Round 3
// baseline (283.919 us; speedup 1.0000x reference)
//
#include <hip/hip_runtime.h>

// BEiT self-attention: B=64, S=197, D=768, H=12, HD=64
// Pipeline:
//   1. k_convert_h   : hidden fp32 -> bf16, M padded 12608->12672
//   2. k_convert_w   : wq/wk/wv fp32 -> combined bf16 W [2304][768] (row-major [n][k], B^T form)
//   3. k_bias_expand : bias_table[rel_index] -> dense [H][S][S] fp32
//   4. k_gemm_qkv    : m97-style MFMA GEMM w/ global_load_lds(16B) + XOR-swizzled LDS;
//                      Q pre-scaled by 0.125 in epilogue
//   5. k_attn_mfma   : per-(b,h) block, 2 groups x 4 cooperating waves; K from global,
//                      V^T + P in swizzled LDS (49KB -> 3 blocks/CU)

#define S_LEN 197
#define HEADS 12
#define HDIM 64
#define DMODEL 768
#define BATCH 64
#define MROWS (BATCH * S_LEN) /* 12608 */
#define MPAD 12672
#define NCOLS (3 * DMODEL) /* 2304 */
#define KDIM DMODEL
#define QKV_ELEMS ((size_t)BATCH * HEADS * S_LEN * HDIM) /* 9,682,944 */

#define NQT 13     /* ceil(197/16) query tiles */
#define VT_ST 256  /* ushorts per Vt row: 32 chunks of 16B (swizzle-safe) */
#define P_ST 256   /* ushorts per P row */

typedef __attribute__((ext_vector_type(8))) short short8;
typedef __attribute__((ext_vector_type(4))) float floatx4;

// global -> LDS direct DMA, 16B per lane; LDS dest = wave-uniform base + lane*16
#define GLD16(gp, lp)                                                                  \
  __builtin_amdgcn_global_load_lds(                                                    \
      (const __attribute__((address_space(1))) unsigned int*)(gp),                     \
      (__attribute__((address_space(3))) unsigned int*)(lp), 16, 0, 0)

__device__ __forceinline__ ushort f2bf(float f) {
  union { float f; unsigned int i; } x;
  x.f = f;
  unsigned int r = x.i + 0x7fffu + ((x.i >> 16) & 1u); // round-to-nearest-even
  return (ushort)(r >> 16);
}

__global__ void k_convert_h(const float* __restrict__ hs, ushort* __restrict__ hbf) {
  int col = blockIdx.x * 256 + threadIdx.x; // < 768
  int row = blockIdx.y;                     // < MPAD
  float v = (row < MROWS) ? hs[(size_t)row * DMODEL + col] : 0.f;
  hbf[(size_t)row * DMODEL + col] = f2bf(v);
}

__global__ void k_convert_w(const float* __restrict__ wq, const float* __restrict__ wk,
                            const float* __restrict__ wv, ushort* __restrict__ wbf) {
  int col = blockIdx.x * 256 + threadIdx.x; // < 768
  int row = blockIdx.y;                     // < 2304
  const float* src = (row < DMODEL) ? &wq[(size_t)row * DMODEL]
                     : (row < 2 * DMODEL) ? &wk[(size_t)(row - DMODEL) * DMODEL]
                                          : &wv[(size_t)(row - 2 * DMODEL) * DMODEL];
  wbf[(size_t)row * DMODEL + col] = f2bf(src[col]);
}

__global__ void k_bias_expand(const float* __restrict__ bt, const int* __restrict__ ridx,
                              float* __restrict__ biasb) {
  int idx = blockIdx.x * 256 + threadIdx.x;
  if (idx >= HEADS * S_LEN * S_LEN) return;
  int h = idx / (S_LEN * S_LEN);
  int r = idx - h * (S_LEN * S_LEN);
  biasb[idx] = bt[ridx[r] * HEADS + h];
}

// 128x128 tile, BK=32, 4 waves x 4x4 mfma_f32_16x16x32_bf16.
// Staging via global_load_lds width=16. LDS unpadded stride-32 rows (4 chunks of 16B);
// position p holds chunk kc=((p^row)&3)*8 of row p>>2 -> fragment ds_read_b128 2-way max.
__global__ __launch_bounds__(256) void k_gemm_qkv(
    const ushort* __restrict__ A, const ushort* __restrict__ W,
    const float* __restrict__ bq, const float* __restrict__ bv,
    ushort* __restrict__ Qb, ushort* __restrict__ Kb, ushort* __restrict__ Vb) {
  __shared__ __align__(16) ushort As[128 * 32];
  __shared__ __align__(16) ushort Bs[128 * 32];
  int tid = threadIdx.x;
  int wave = tid >> 6, lane = tid & 63;
  int quad = lane >> 4, l16 = lane & 15;
  int m0 = blockIdx.y * 128, n0 = blockIdx.x * 128;
  int wm = (wave & 1) * 64, wn = (wave >> 1) * 64;
  int swz = (quad ^ (l16 & 3)) << 3; // fragment-read chunk swizzle (row&3 == l16&3)

  floatx4 acc[4][4];
  floatx4 z = {0.f, 0.f, 0.f, 0.f};
#pragma unroll
  for (int i = 0; i < 4; ++i)
#pragma unroll
    for (int j = 0; j < 4; ++j) acc[i][j] = z;

  int p0 = wave * 128 + lane;
  for (int kb = 0; kb < KDIM; kb += 32) {
    const ushort* Arow = A + (size_t)m0 * KDIM + kb;
    const ushort* Brow = W + (size_t)n0 * KDIM + kb;
#pragma unroll
    for (int s = 0; s < 2; ++s) {
      int p = p0 + s * 64;
      int r = p >> 2;
      int kc = ((p ^ r) & 3) << 3;
      GLD16(&Arow[(size_t)r * KDIM + kc], &As[p * 8]);
      GLD16(&Brow[(size_t)r * KDIM + kc], &Bs[p * 8]);
    }
    __syncthreads();
    short8 af[4], bfr[4];
#pragma unroll
    for (int i = 0; i < 4; ++i) {
      af[i] = *(const short8*)(&As[(wm + i * 16 + l16) * 32 + swz]);
      bfr[i] = *(const short8*)(&Bs[(wn + i * 16 + l16) * 32 + swz]);
    }
#pragma unroll
    for (int i = 0; i < 4; ++i)
#pragma unroll
      for (int j = 0; j < 4; ++j)
        acc[i][j] = __builtin_amdgcn_mfma_f32_16x16x32_bf16(af[i], bfr[j], acc[i][j], 0, 0, 0);
    __syncthreads();
  }

  // epilogue: C/D layout col=lane&15, row=quad*4+r. Q gets *0.125 (exact in bf16).
#pragma unroll
  for (int j = 0; j < 4; ++j) {
    int col = n0 + wn + j * 16 + l16; // < 2304
    int which = col / DMODEL;         // 0=q 1=k 2=v
    int rem = col - which * DMODEL;
    int hh = rem >> 6;
    int d = rem & 63;
    float bias = (which == 0) ? bq[col] : ((which == 2) ? bv[col - 2 * DMODEL] : 0.f);
    float scl = (which == 0) ? 0.125f : 1.0f;
    ushort* dst = (which == 0) ? Qb : ((which == 1) ? Kb : Vb);
#pragma unroll
    for (int i = 0; i < 4; ++i) {
#pragma unroll
      for (int r = 0; r < 4; ++r) {
        int m = m0 + wm + i * 16 + quad * 4 + r;
        if (m < MROWS) {
          int bb = m / S_LEN;
          int ss = m - bb * S_LEN;
          dst[((size_t)(bb * HEADS + hh) * S_LEN + ss) * HDIM + d] =
              f2bf((acc[i][j][r] + bias) * scl);
        }
      }
    }
  }
}

// MFMA attention. One block per (b,h), 8 waves in 2 groups of 4.
// Group g handles qt = 2*it+g. Within a group: scores split over kt (4/3/3/3 per wave),
// cross-wave max/sum via small LDS buffer; PV split over d (16 cols per wave).
// K/Q read directly from global (bf16, 16B/lane, L1/L2-resident).
// Vt [d][key] and P [q][key] in LDS, XOR chunk-swizzled (stride 256 ushorts = 32 chunks).
__global__ __launch_bounds__(512) void k_attn_mfma(
    const ushort* __restrict__ Qb, const ushort* __restrict__ Kb,
    const ushort* __restrict__ Vb, const float* __restrict__ biasb,
    float* __restrict__ out) {
  __shared__ __align__(16) ushort Vt[HDIM * VT_ST];   // 32768 B
  __shared__ __align__(16) ushort Ps[2 * 16 * P_ST];  // 16384 B
  __shared__ __align__(16) float red[2 * 16 * 8];     // [g][row][0..3 max | 4..7 sum]
  int bh = blockIdx.x;
  int b = bh / HEADS, h = bh - b * HEADS;
  int tid = threadIdx.x;
  int wave = tid >> 6, lane = tid & 63;
  int quad = lane >> 4, l16 = lane & 15;
  int g = wave >> 2, wq = wave & 3;

  { // zero Vt + P (pad cols/chunks must be 0.0, not poison)
    uint4 z4 = {0u, 0u, 0u, 0u};
    for (int i = tid; i < HDIM * VT_ST / 8; i += 512) ((uint4*)Vt)[i] = z4;
    for (int i = tid; i < 2 * 16 * P_ST / 8; i += 512) ((uint4*)Ps)[i] = z4;
  }
  __syncthreads();

  const ushort* Vg = Vb + (size_t)bh * S_LEN * HDIM;
  for (int idx = tid; idx < S_LEN * 32; idx += 512) { // transpose V -> Vt (swizzled)
    int key = idx >> 5;
    int d = (idx & 31) * 2;
    unsigned int v = *(const unsigned int*)&Vg[key * HDIM + d];
    int co = key & 7, ch = key >> 3;
    Vt[d * VT_ST + ((ch ^ (d & 7)) << 3) + co] = (ushort)(v & 0xffffu);
    Vt[(d + 1) * VT_ST + ((ch ^ ((d + 1) & 7)) << 3) + co] = (ushort)(v >> 16);
  }
  __syncthreads();

  const ushort* Qg = Qb + (size_t)bh * S_LEN * HDIM;
  const ushort* Kg = Kb + (size_t)bh * S_LEN * HDIM;
  const float* biasH = biasb + (size_t)h * S_LEN * S_LEN;
  ushort* Pg = Ps + g * 16 * P_ST;
  float* redg = red + g * 16 * 8;
  int kt0 = (wq == 0) ? 0 : (3 * wq + 1); // kt ranges {0-3, 4-6, 7-9, 10-12}
  int ktn = (wq == 0) ? 4 : 3;

  for (int it = 0; it < 7; ++it) {
    int qt = 2 * it + g;
    bool active = (qt < NQT); // wave-uniform; barriers stay outside
    floatx4 sacc[4];
    float mx[4];
    if (active) {
      int q0 = qt * 16;
      // Q a-frag: [m=l16][k=quad*8+j]; Q pre-scaled by 0.125 in GEMM epilogue.
      short8 qa0 = *(const short8*)&Qg[(q0 + l16) * HDIM + quad * 8];
      short8 qa1 = *(const short8*)&Qg[(q0 + l16) * HDIM + 32 + quad * 8];
      int qrow = q0 + quad * 4;
#pragma unroll
      for (int t = 0; t < 4; ++t) {
        if (t < ktn) {
          int key = (kt0 + t) * 16 + l16;
          int keyc = (key < S_LEN) ? key : (S_LEN - 1);
          floatx4 cin; // bias as MFMA C-init; -1e30 masks pad rows/cols
#pragma unroll
          for (int r = 0; r < 4; ++r) {
            int q = qrow + r;
            int qc = (q < S_LEN) ? q : (S_LEN - 1);
            float bv = biasH[qc * S_LEN + keyc];
            cin[r] = (q < S_LEN && key < S_LEN) ? bv : -1e30f;
          }
          // K b-frag straight from global: [n=key=l16-group][k=d]
          short8 kb0 = *(const short8*)&Kg[key * HDIM + quad * 8];
          short8 kb1 = *(const short8*)&Kg[key * HDIM + 32 + quad * 8];
          floatx4 s1 = __builtin_amdgcn_mfma_f32_16x16x32_bf16(qa0, kb0, cin, 0, 0, 0);
          sacc[t] = __builtin_amdgcn_mfma_f32_16x16x32_bf16(qa1, kb1, s1, 0, 0, 0);
        }
      }
      // partial row-max over this wave's kts (row = quad*4+r, cols on l16)
#pragma unroll
      for (int r = 0; r < 4; ++r) {
        float m = -3e38f;
#pragma unroll
        for (int t = 0; t < 4; ++t)
          if (t < ktn) m = fmaxf(m, sacc[t][r]);
        m = fmaxf(m, __shfl_xor(m, 1));
        m = fmaxf(m, __shfl_xor(m, 2));
        m = fmaxf(m, __shfl_xor(m, 4));
        m = fmaxf(m, __shfl_xor(m, 8));
        mx[r] = m;
      }
      if (l16 == 0) {
#pragma unroll
        for (int r = 0; r < 4; ++r) redg[(quad * 4 + r) * 8 + wq] = mx[r];
      }
    }
    __syncthreads();
    if (active) {
      float sum[4];
#pragma unroll
      for (int r = 0; r < 4; ++r) {
        floatx4 mp = *(const floatx4*)&redg[(quad * 4 + r) * 8];
        mx[r] = fmaxf(fmaxf(mp[0], mp[1]), fmaxf(mp[2], mp[3]));
        sum[r] = 0.f;
      }
#pragma unroll
      for (int t = 0; t < 4; ++t) {
        if (t < ktn) {
          int col = (kt0 + t) * 16 + l16;
          int cpos = col >> 3, coff = col & 7;
#pragma unroll
          for (int r = 0; r < 4; ++r) {
            int row = quad * 4 + r;
            float e = __expf(sacc[t][r] - mx[r]);
            sum[r] += e;
            Pg[row * P_ST + ((cpos ^ (row & 7)) << 3) + coff] = f2bf(e); // unnormalized
          }
        }
      }
#pragma unroll
      for (int r = 0; r < 4; ++r) {
        float s = sum[r];
        s += __shfl_xor(s, 1);
        s += __shfl_xor(s, 2);
        s += __shfl_xor(s, 4);
        s += __shfl_xor(s, 8);
        sum[r] = s;
      }
      if (l16 == 0) {
#pragma unroll
        for (int r = 0; r < 4; ++r) redg[(quad * 4 + r) * 8 + 4 + wq] = sum[r];
      }
    }
    __syncthreads();
    if (active) {
      // PV: this wave computes O cols d = wq*16 + l16; A=P (LDS), B=Vt (LDS)
      floatx4 oacc = {0.f, 0.f, 0.f, 0.f};
      int d = wq * 16 + l16;
#pragma unroll
      for (int kk = 0; kk < 7; ++kk) {
        int cidx = 4 * kk + quad;
        short8 pa = *(const short8*)&Pg[l16 * P_ST + ((cidx ^ (l16 & 7)) << 3)];
        short8 vb2 = *(const short8*)&Vt[d * VT_ST + ((cidx ^ (d & 7)) << 3)];
        oacc = __builtin_amdgcn_mfma_f32_16x16x32_bf16(pa, vb2, oacc, 0, 0, 0);
      }
      int q0 = qt * 16;
      float* outg = out + (size_t)b * S_LEN * DMODEL + h * HDIM + d;
#pragma unroll
      for (int r = 0; r < 4; ++r) {
        int row = quad * 4 + r;
        floatx4 sp = *(const floatx4*)&redg[row * 8 + 4];
        float tot = sp[0] + sp[1] + sp[2] + sp[3];
        int q = q0 + row;
        if (q < S_LEN) outg[(size_t)q * DMODEL] = oacc[r] * (1.f / tot);
      }
    }
    // next iteration's first barrier orders P reads (here) vs P writes (next it)
  }
}

extern "C" void kernel_launch(void* const* d_in, const int* in_sizes, int n_in,
                              void* d_out, int out_size, void* d_ws, size_t ws_size,
                              hipStream_t stream) {
  const float* hs = (const float*)d_in[0];
  const float* wq = (const float*)d_in[1];
  const float* bq = (const float*)d_in[2];
  const float* wk = (const float*)d_in[3];
  const float* wv = (const float*)d_in[4];
  const float* bv = (const float*)d_in[5];
  const float* bt = (const float*)d_in[6];
  const int* ridx = (const int*)d_in[7];
  float* out = (float*)d_out;

  // workspace layout (~100 MB)
  ushort* hbf = (ushort*)d_ws;                 // MPAD*768 bf16
  ushort* wbf = hbf + (size_t)MPAD * KDIM;     // 2304*768 bf16
  ushort* Qb = wbf + (size_t)NCOLS * KDIM;     // [B,H,S,HD] bf16
  ushort* Kb = Qb + QKV_ELEMS;                 // (small tail over-reads land in next region)
  ushort* Vb = Kb + QKV_ELEMS;
  float* biasb = (float*)(Vb + QKV_ELEMS);     // [H,S,S] fp32

  k_convert_h<<<dim3(3, MPAD), 256, 0, stream>>>(hs, hbf);
  k_convert_w<<<dim3(3, NCOLS), 256, 0, stream>>>(wq, wk, wv, wbf);
  int nb = (HEADS * S_LEN * S_LEN + 255) / 256;
  k_bias_expand<<<nb, 256, 0, stream>>>(bt, ridx, biasb);
  k_gemm_qkv<<<dim3(NCOLS / 128, MPAD / 128), 256, 0, stream>>>(hbf, wbf, bq, bv, Qb, Kb, Vb);
  k_attn_mfma<<<BATCH * HEADS, 512, 0, stream>>>(Qb, Kb, Vb, biasb, out);
}

// Round 4
// 253.517 us; speedup vs baseline: 1.1199x; 1.1199x over previous
//
#include <hip/hip_runtime.h>

// BEiT self-attention: B=64, S=197, D=768, H=12, HD=64
// Pipeline:
//   1. k_convert_h   : hidden fp32 -> bf16, M padded 12608->12672 (pad rows zero)
//   2. k_convert_w   : wq/wk/wv fp32 -> combined bf16 W [2304][768] (B^T form)
//   3. k_bias_expand : bias_table[rel_index] -> MFMA-C-fragment layout [h][qt][t][lane][4],
//                      -1e30 masking for key>=197 pre-baked
//   4. k_gemm_qkv    : MFMA GEMM -> single row-major C [12672][2304] bf16 via swizzled-LDS
//                      repack epilogue (full-line dwordx4 stores); Q cols pre-scaled 0.125
//   5. k_attn_mfma   : transposed attention S^T=K*Q^T, O^T=V^T*P^T; only V^T in LDS;
//                      P transform via quad-shfl (no LDS round-trip); no loop barriers

#define S_LEN 197
#define HEADS 12
#define HDIM 64
#define DMODEL 768
#define BATCH 64
#define MROWS (BATCH * S_LEN) /* 12608 */
#define MPAD 12672
#define NCOLS (3 * DMODEL) /* 2304 */
#define KDIM DMODEL
#define NQT 13 /* ceil(197/16) */

typedef __attribute__((ext_vector_type(8))) short short8;
typedef __attribute__((ext_vector_type(4))) float floatx4;

#define GLD16(gp, lp)                                                                  \
  __builtin_amdgcn_global_load_lds(                                                    \
      (const __attribute__((address_space(1))) unsigned int*)(gp),                     \
      (__attribute__((address_space(3))) unsigned int*)(lp), 16, 0, 0)

__device__ __forceinline__ ushort f2bf(float f) {
  union { float f; unsigned int i; } x;
  x.f = f;
  unsigned int r = x.i + 0x7fffu + ((x.i >> 16) & 1u); // RNE
  return (ushort)(r >> 16);
}

__global__ void k_convert_h(const float* __restrict__ hs, ushort* __restrict__ hbf) {
  int col = blockIdx.x * 256 + threadIdx.x;
  int row = blockIdx.y;
  float v = (row < MROWS) ? hs[(size_t)row * DMODEL + col] : 0.f;
  hbf[(size_t)row * DMODEL + col] = f2bf(v);
}

__global__ void k_convert_w(const float* __restrict__ wq, const float* __restrict__ wk,
                            const float* __restrict__ wv, ushort* __restrict__ wbf) {
  int col = blockIdx.x * 256 + threadIdx.x;
  int row = blockIdx.y;
  const float* src = (row < DMODEL) ? &wq[(size_t)row * DMODEL]
                     : (row < 2 * DMODEL) ? &wk[(size_t)(row - DMODEL) * DMODEL]
                                          : &wv[(size_t)(row - 2 * DMODEL) * DMODEL];
  wbf[(size_t)row * DMODEL + col] = f2bf(src[col]);
}

// biasF[h][qt][t][lane][r]: C-fragment layout of S^T tile (row=key=quad*4+r, col=q=l16)
__global__ void k_bias_expand(const float* __restrict__ bt, const int* __restrict__ ridx,
                              float* __restrict__ biasF) {
  int idx = blockIdx.x * 256 + threadIdx.x; // < 12*13*13*64
  if (idx >= HEADS * NQT * NQT * 64) return;
  int lane = idx & 63;
  int rest = idx >> 6;
  int t = rest % NQT;
  int rest2 = rest / NQT;
  int qt = rest2 % NQT;
  int h = rest2 / NQT;
  int l16 = lane & 15, quad = lane >> 4;
  int q = qt * 16 + l16;
#pragma unroll
  for (int r = 0; r < 4; ++r) {
    int key = t * 16 + quad * 4 + r;
    float v = -1e30f;
    if (q < S_LEN && key < S_LEN) v = bt[ridx[q * S_LEN + key] * HEADS + h];
    biasF[(size_t)idx * 4 + r] = v;
  }
}

// 128x128 tile, BK=32, global_load_lds staging (chunk-swizzled), LDS-repack epilogue.
__global__ __launch_bounds__(256) void k_gemm_qkv(
    const ushort* __restrict__ A, const ushort* __restrict__ W,
    const float* __restrict__ bq, const float* __restrict__ bv,
    ushort* __restrict__ Cb) {
  __shared__ __align__(16) ushort SH[128 * 128]; // 32 KB: staging (16 KB) U epilogue tile
  ushort* As = SH;
  ushort* Bs = SH + 128 * 32;
  int tid = threadIdx.x;
  int wave = tid >> 6, lane = tid & 63;
  int quad = lane >> 4, l16 = lane & 15;
  int m0 = blockIdx.y * 128, n0 = blockIdx.x * 128;
  int wm = (wave & 1) * 64, wn = (wave >> 1) * 64;
  int swz = (quad ^ (l16 & 3)) << 3;

  floatx4 acc[4][4];
  floatx4 z = {0.f, 0.f, 0.f, 0.f};
#pragma unroll
  for (int i = 0; i < 4; ++i)
#pragma unroll
    for (int j = 0; j < 4; ++j) acc[i][j] = z;

  int p0 = wave * 128 + lane;
  for (int kb = 0; kb < KDIM; kb += 32) {
    const ushort* Arow = A + (size_t)m0 * KDIM + kb;
    const ushort* Brow = W + (size_t)n0 * KDIM + kb;
#pragma unroll
    for (int s = 0; s < 2; ++s) {
      int p = p0 + s * 64;
      int r = p >> 2;
      int kc = ((p ^ r) & 3) << 3;
      GLD16(&Arow[(size_t)r * KDIM + kc], &As[p * 8]);
      GLD16(&Brow[(size_t)r * KDIM + kc], &Bs[p * 8]);
    }
    __syncthreads();
    short8 af[4], bfr[4];
#pragma unroll
    for (int i = 0; i < 4; ++i) {
      af[i] = *(const short8*)(&As[(wm + i * 16 + l16) * 32 + swz]);
      bfr[i] = *(const short8*)(&Bs[(wn + i * 16 + l16) * 32 + swz]);
    }
#pragma unroll
    for (int i = 0; i < 4; ++i)
#pragma unroll
      for (int j = 0; j < 4; ++j)
        acc[i][j] = __builtin_amdgcn_mfma_f32_16x16x32_bf16(af[i], bfr[j], acc[i][j], 0, 0, 0);
    __syncthreads(); // also guards SH reuse below on last iteration
  }

  // epilogue: acc (+bias, q-scale) -> swizzled bf16 tile in SH -> full-line dwordx4 stores
#pragma unroll
  for (int j = 0; j < 4; ++j) {
    int coln = wn + j * 16 + l16; // block-local col 0..127
    int col = n0 + coln;          // global col < 2304
    float bias = (col < DMODEL) ? bq[col] : ((col >= 2 * DMODEL) ? bv[col - 2 * DMODEL] : 0.f);
    float scl = (col < DMODEL) ? 0.125f : 1.0f;
#pragma unroll
    for (int i = 0; i < 4; ++i)
#pragma unroll
      for (int r = 0; r < 4; ++r) {
        int row = wm + i * 16 + quad * 4 + r;
        int ch = (coln >> 3) ^ (row & 7); // swizzle low 3 bits of 16B-chunk index
        SH[row * 128 + (ch << 3) + (coln & 7)] = f2bf((acc[i][j][r] + bias) * scl);
      }
  }
  __syncthreads();
  // stores: 2 passes x 4 chunks; 4 lanes cover 64B contiguous, 16 rows per instruction
#pragma unroll
  for (int p = 0; p < 2; ++p) {
    int row = p * 64 + wave * 16 + (lane >> 2);
    int q4 = lane & 3;
    ushort* gC = Cb + (size_t)(m0 + row) * NCOLS + n0;
#pragma unroll
    for (int c = 0; c < 4; ++c) {
      int cp = c * 4 + q4; // chunk pos 0..15
      int ch = cp ^ (row & 7);
      *(uint4*)&gC[cp * 8] = *(const uint4*)&SH[row * 128 + (ch << 3)];
    }
  }
}

// Transposed MFMA attention. One block per (b,h), 4 independent waves (qt = wave+4k).
// S^T = K*Q^T : C-layout row=key=quad*4+r, col=q=l16. Softmax per column (2 shfls).
// P^T -> PV B-frag via quad-transpose shfl (no LDS). O^T = V^T * P^T, V^T in swizzled LDS.
__global__ __launch_bounds__(256) void k_attn_mfma(
    const ushort* __restrict__ Cb0, const float* __restrict__ biasF,
    float* __restrict__ out) {
  __shared__ __align__(16) ushort Vt[HDIM * 256]; // 32 KB, [d][key] swizzled
  int bh = blockIdx.x;
  int b = bh / HEADS, h = bh - b * HEADS;
  int tid = threadIdx.x;
  int wave = tid >> 6, lane = tid & 63;
  int quad = lane >> 4, l16 = lane & 15;
  const ushort* Cb = Cb0 + (size_t)b * S_LEN * NCOLS;
  const int qoff = h * HDIM, koff = DMODEL + h * HDIM, voff = 2 * DMODEL + h * HDIM;

  { // zero Vt (key cols 197..255 must be 0.0)
    uint4 z4 = {0u, 0u, 0u, 0u};
    for (int i = tid; i < HDIM * 256 / 8; i += 256) ((uint4*)Vt)[i] = z4;
  }
  __syncthreads();
  for (int idx = tid; idx < S_LEN * 32; idx += 256) { // V -> V^T (swizzled scatter)
    int key = idx >> 5, dp = (idx & 31) * 2;
    unsigned int v = *(const unsigned int*)&Cb[(size_t)key * NCOLS + voff + dp];
    int ch = key >> 3, co = key & 7;
    Vt[dp * 256 + ((ch ^ (dp & 7)) << 3) + co] = (ushort)(v & 0xffffu);
    Vt[(dp + 1) * 256 + ((ch ^ ((dp + 1) & 7)) << 3) + co] = (ushort)(v >> 16);
  }
  __syncthreads(); // last barrier; waves independent below

  for (int qt = wave; qt < NQT; qt += 4) {
    int q0 = qt * 16;
    int q = q0 + l16; // may reach 207: rows stay inside C buffer (garbage masked by bias)
    short8 qb0 = *(const short8*)&Cb[(size_t)q * NCOLS + qoff + quad * 8];
    short8 qb1 = *(const short8*)&Cb[(size_t)q * NCOLS + qoff + 32 + quad * 8];
    const float* bF = biasF + ((size_t)((h * NQT + qt) * NQT) * 64 + lane) * 4;

    floatx4 sacc[NQT];
#pragma unroll
    for (int t = 0; t < NQT; ++t) {
      floatx4 cin = *(const floatx4*)&bF[t * 256]; // bias as MFMA C-init (masking baked in)
      short8 ka0 = *(const short8*)&Cb[(size_t)(t * 16 + l16) * NCOLS + koff + quad * 8];
      short8 ka1 = *(const short8*)&Cb[(size_t)(t * 16 + l16) * NCOLS + koff + 32 + quad * 8];
      floatx4 s1 = __builtin_amdgcn_mfma_f32_16x16x32_bf16(ka0, qb0, cin, 0, 0, 0);
      sacc[t] = __builtin_amdgcn_mfma_f32_16x16x32_bf16(ka1, qb1, s1, 0, 0, 0);
    }

    // softmax over keys (spread across quads+regs+tiles at fixed col q)
    float mx = -3e38f;
#pragma unroll
    for (int t = 0; t < NQT; ++t)
#pragma unroll
      for (int r = 0; r < 4; ++r) mx = fmaxf(mx, sacc[t][r]);
    mx = fmaxf(mx, __shfl_xor(mx, 16));
    mx = fmaxf(mx, __shfl_xor(mx, 32));
    float sum = 0.f;
    unsigned int pbf[NQT][2]; // packed bf16 pairs (rows 2r,2r+1), unnormalized
#pragma unroll
    for (int t = 0; t < NQT; ++t) {
      float e0 = __expf(sacc[t][0] - mx), e1 = __expf(sacc[t][1] - mx);
      float e2 = __expf(sacc[t][2] - mx), e3 = __expf(sacc[t][3] - mx);
      sum += (e0 + e1) + (e2 + e3);
      union { float f; unsigned int u; } a, bb, c, d;
      a.f = e0; bb.f = e1; c.f = e2; d.f = e3;
      pbf[t][0] = ((a.u + 0x8000u) >> 16) | ((bb.u + 0x8000u) & 0xffff0000u);
      pbf[t][1] = ((c.u + 0x8000u) >> 16) | ((d.u + 0x8000u) & 0xffff0000u);
    }
    sum += __shfl_xor(sum, 16);
    sum += __shfl_xor(sum, 32);
    float inv = 1.f / sum;

    // PV: O^T[d][q]; B-frag(P) lane(quad,l16) needs keys kk*32+quad*8+j of col q=l16
    floatx4 oacc[4];
    floatx4 zz = {0.f, 0.f, 0.f, 0.f};
#pragma unroll
    for (int dt = 0; dt < 4; ++dt) oacc[dt] = zz;
    int sel0 = ((quad & 1) * 2) * 16 + l16; // src lane: quad (quad&1)*2, same l16
    int sel1 = sel0 + 16;
#pragma unroll
    for (int kk = 0; kk < 7; ++kk) {
      unsigned int u0 = 0, u1 = 0, u2 = 0, u3 = 0;
#pragma unroll
      for (int half = 0; half < 2; ++half) { // half = target quad>>1 selects tile
        int t = 2 * kk + half;
        if (t < NQT) {
          unsigned int v0 = __shfl((int)pbf[t][0], sel0);
          unsigned int v1 = __shfl((int)pbf[t][1], sel0);
          unsigned int v2 = __shfl((int)pbf[t][0], sel1);
          unsigned int v3 = __shfl((int)pbf[t][1], sel1);
          if ((quad >> 1) == half) { u0 = v0; u1 = v1; u2 = v2; u3 = v3; }
        }
      }
      union { uint4 u; short8 s; } pf;
      pf.u.x = u0; pf.u.y = u1; pf.u.z = u2; pf.u.w = u3;
#pragma unroll
      for (int dt = 0; dt < 4; ++dt) {
        int d = dt * 16 + l16;
        short8 vf = *(const short8*)&Vt[d * 256 + (((kk * 4 + quad) ^ (d & 7)) << 3)];
        oacc[dt] = __builtin_amdgcn_mfma_f32_16x16x32_bf16(vf, pf.s, oacc[dt], 0, 0, 0);
      }
    }

    // O^T C-layout: row=d=dt*16+quad*4+r, col=q=l16 -> per-lane float4 of consecutive d
    if (q < S_LEN) {
      float* og = out + ((size_t)b * S_LEN + q) * DMODEL + h * HDIM + quad * 4;
#pragma unroll
      for (int dt = 0; dt < 4; ++dt) {
        floatx4 o = oacc[dt];
        float4 st = make_float4(o[0] * inv, o[1] * inv, o[2] * inv, o[3] * inv);
        *(float4*)&og[dt * 16] = st;
      }
    }
  }
}

extern "C" void kernel_launch(void* const* d_in, const int* in_sizes, int n_in,
                              void* d_out, int out_size, void* d_ws, size_t ws_size,
                              hipStream_t stream) {
  const float* hs = (const float*)d_in[0];
  const float* wq = (const float*)d_in[1];
  const float* bq = (const float*)d_in[2];
  const float* wk = (const float*)d_in[3];
  const float* wv = (const float*)d_in[4];
  const float* bv = (const float*)d_in[5];
  const float* bt = (const float*)d_in[6];
  const int* ridx = (const int*)d_in[7];
  float* out = (float*)d_out;

  // workspace (~83.5 MB)
  ushort* hbf = (ushort*)d_ws;              // [12672][768] bf16
  ushort* wbf = hbf + (size_t)MPAD * KDIM;  // [2304][768] bf16
  ushort* Cb = wbf + (size_t)NCOLS * KDIM;  // [12672][2304] bf16 (QKV combined)
  float* biasF = (float*)(Cb + (size_t)MPAD * NCOLS); // [12][13][13][64][4] fp32

  k_convert_h<<<dim3(3, MPAD), 256, 0, stream>>>(hs, hbf);
  k_convert_w<<<dim3(3, NCOLS), 256, 0, stream>>>(wq, wk, wv, wbf);
  int nbias = (HEADS * NQT * NQT * 64 + 255) / 256;
  k_bias_expand<<<nbias, 256, 0, stream>>>(bt, ridx, biasF);
  k_gemm_qkv<<<dim3(NCOLS / 128, MPAD / 128), 256, 0, stream>>>(hbf, wbf, bq, bv, Cb);
  k_attn_mfma<<<BATCH * HEADS, 256, 0, stream>>>(Cb, biasF, out);
}

// Round 5
// 237.571 us; speedup vs baseline: 1.1951x; 1.0671x over previous
//
#include <hip/hip_runtime.h>

// BEiT self-attention: B=64, S=197, D=768, H=12, HD=64
// Pipeline:
//   1. k_prep      : fused grid-stride prep — hidden fp32->bf16 (pad rows zero),
//                    W combine fp32->bf16 [2304][768], bias -> MFMA-C-frag layout
//   2. k_gemm_qkv  : MFMA GEMM -> row-major C [12672][2304] bf16; global_load_lds staging
//                    with corrected XOR swizzle; XCD-aware tile remap; Q pre-scaled 0.125
//   3. k_attn_mfma : transposed attention S^T=K*Q^T, O^T=V^T*P^T; K a-frags + V^T in LDS;
//                    P via quad-shfl transform; no barriers in main loop

#define S_LEN 197
#define HEADS 12
#define HDIM 64
#define DMODEL 768
#define BATCH 64
#define MROWS (BATCH * S_LEN) /* 12608 */
#define MPAD 12672
#define NCOLS (3 * DMODEL) /* 2304 */
#define KDIM DMODEL
#define NQT 13 /* ceil(197/16) */
#define NTILE (NCOLS / 128) /* 18 */
#define MTILE (MPAD / 128)  /* 99 */

typedef __attribute__((ext_vector_type(8))) short short8;
typedef __attribute__((ext_vector_type(4))) float floatx4;

#define GLD16(gp, lp)                                                                  \
  __builtin_amdgcn_global_load_lds(                                                    \
      (const __attribute__((address_space(1))) unsigned int*)(gp),                     \
      (__attribute__((address_space(3))) unsigned int*)(lp), 16, 0, 0)

__device__ __forceinline__ ushort f2bf(float f) {
  union { float f; unsigned int i; } x;
  x.f = f;
  unsigned int r = x.i + 0x7fffu + ((x.i >> 16) & 1u); // RNE
  return (ushort)(r >> 16);
}

// fused prep: one launch, grid-stride over three independent sections
__global__ __launch_bounds__(256) void k_prep(
    const float* __restrict__ hs, const float* __restrict__ wq,
    const float* __restrict__ wk, const float* __restrict__ wv,
    const float* __restrict__ bt, const int* __restrict__ ridx,
    ushort* __restrict__ hbf, ushort* __restrict__ wbf, float* __restrict__ biasF) {
  int gid = blockIdx.x * 256 + threadIdx.x;
  int gsz = gridDim.x * 256;
  // hidden -> bf16, rows >= MROWS zeroed
  for (int i = gid; i < MPAD * KDIM / 8; i += gsz) {
    int base = i * 8;
    int row = base / KDIM;
    ushort o[8];
    if (row < MROWS) {
      const float* s = hs + (size_t)base;
#pragma unroll
      for (int e = 0; e < 8; ++e) o[e] = f2bf(s[e]);
    } else {
#pragma unroll
      for (int e = 0; e < 8; ++e) o[e] = 0;
    }
    *(uint4*)&hbf[base] = *(const uint4*)o;
  }
  // weights -> combined bf16 [2304][768]
  for (int i = gid; i < NCOLS * KDIM / 8; i += gsz) {
    int base = i * 8;
    int row = base / KDIM;
    int col = base - row * KDIM;
    const float* src = (row < DMODEL) ? &wq[(size_t)row * KDIM]
                       : (row < 2 * DMODEL) ? &wk[(size_t)(row - DMODEL) * KDIM]
                                            : &wv[(size_t)(row - 2 * DMODEL) * KDIM];
    ushort o[8];
#pragma unroll
    for (int e = 0; e < 8; ++e) o[e] = f2bf(src[col + e]);
    *(uint4*)&wbf[base] = *(const uint4*)o;
  }
  // biasF[h][qt][t][lane][r]: C-frag of S^T tile (row=key=quad*4+r, col=q=l16); mask baked
  for (int idx = gid; idx < HEADS * NQT * NQT * 64; idx += gsz) {
    int lane = idx & 63;
    int rest = idx >> 6;
    int t = rest % NQT;
    int rest2 = rest / NQT;
    int qt = rest2 % NQT;
    int h = rest2 / NQT;
    int l16 = lane & 15, quad = lane >> 4;
    int q = qt * 16 + l16;
    floatx4 v;
#pragma unroll
    for (int r = 0; r < 4; ++r) {
      int key = t * 16 + quad * 4 + r;
      float x = -1e30f;
      if (q < S_LEN && key < S_LEN) x = bt[ridx[q * S_LEN + key] * HEADS + h];
      v[r] = x;
    }
    *(floatx4*)&biasF[(size_t)idx * 4] = v;
  }
}

// 128x128 tile, BK=32, global_load_lds staging. Corrected swizzle: LDS position p
// (row=p>>2, c=p&3) holds global chunk (p&3)^((p>>3)&3); fragment read uses
// chunk = quad ^ ((l16>>1)&3) -> each 8-lane phase covers all 8 bank groups.
__global__ __launch_bounds__(256) void k_gemm_qkv(
    const ushort* __restrict__ A, const ushort* __restrict__ W,
    const float* __restrict__ bq, const float* __restrict__ bv,
    ushort* __restrict__ Cb) {
  __shared__ __align__(16) ushort SH[128 * 128]; // staging (16 KB) U epilogue tile (32 KB)
  ushort* As = SH;
  ushort* Bs = SH + 128 * 32;
  int tid = threadIdx.x;
  int wave = tid >> 6, lane = tid & 63;
  int quad = lane >> 4, l16 = lane & 15;

  // XCD-aware remap: dispatch-linear id round-robins XCDs; give each XCD a
  // contiguous run of m-bands so its L2 working set is ~12 A-slabs + W.
  int linear = blockIdx.y * NTILE + blockIdx.x;
  int m_t, n_t;
  if (linear < 1776) { // 8 * 222
    int g = (linear & 7) * 222 + (linear >> 3);
    m_t = g / NTILE;
    n_t = g - m_t * NTILE;
  } else {
    m_t = linear / NTILE;
    n_t = linear - m_t * NTILE;
  }
  int m0 = m_t * 128, n0 = n_t * 128;
  int wm = (wave & 1) * 64, wn = (wave >> 1) * 64;
  int swz = (quad ^ ((l16 >> 1) & 3)) << 3;

  floatx4 acc[4][4];
  floatx4 z = {0.f, 0.f, 0.f, 0.f};
#pragma unroll
  for (int i = 0; i < 4; ++i)
#pragma unroll
    for (int j = 0; j < 4; ++j) acc[i][j] = z;

  int p0 = wave * 128 + lane;
  for (int kb = 0; kb < KDIM; kb += 32) {
    const ushort* Arow = A + (size_t)m0 * KDIM + kb;
    const ushort* Brow = W + (size_t)n0 * KDIM + kb;
#pragma unroll
    for (int s = 0; s < 2; ++s) {
      int p = p0 + s * 64;
      int r = p >> 2;
      int kc = ((p & 3) ^ ((p >> 3) & 3)) << 3;
      GLD16(&Arow[(size_t)r * KDIM + kc], &As[p * 8]);
      GLD16(&Brow[(size_t)r * KDIM + kc], &Bs[p * 8]);
    }
    __syncthreads();
    short8 af[4], bfr[4];
#pragma unroll
    for (int i = 0; i < 4; ++i) {
      af[i] = *(const short8*)(&As[(wm + i * 16 + l16) * 32 + swz]);
      bfr[i] = *(const short8*)(&Bs[(wn + i * 16 + l16) * 32 + swz]);
    }
#pragma unroll
    for (int i = 0; i < 4; ++i)
#pragma unroll
      for (int j = 0; j < 4; ++j)
        acc[i][j] = __builtin_amdgcn_mfma_f32_16x16x32_bf16(af[i], bfr[j], acc[i][j], 0, 0, 0);
    __syncthreads(); // also guards SH reuse in epilogue on last iteration
  }

  // epilogue: acc (+bias, q-scale) -> swizzled bf16 tile in SH -> full-line dwordx4 stores
#pragma unroll
  for (int j = 0; j < 4; ++j) {
    int coln = wn + j * 16 + l16;
    int col = n0 + coln;
    float bias = (col < DMODEL) ? bq[col] : ((col >= 2 * DMODEL) ? bv[col - 2 * DMODEL] : 0.f);
    float scl = (col < DMODEL) ? 0.125f : 1.0f;
#pragma unroll
    for (int i = 0; i < 4; ++i)
#pragma unroll
      for (int r = 0; r < 4; ++r) {
        int row = wm + i * 16 + quad * 4 + r;
        int ch = (coln >> 3) ^ (row & 7);
        SH[row * 128 + (ch << 3) + (coln & 7)] = f2bf((acc[i][j][r] + bias) * scl);
      }
  }
  __syncthreads();
#pragma unroll
  for (int p = 0; p < 2; ++p) {
    int row = p * 64 + wave * 16 + (lane >> 2);
    int q4 = lane & 3;
    ushort* gC = Cb + (size_t)(m0 + row) * NCOLS + n0;
#pragma unroll
    for (int c = 0; c < 4; ++c) {
      int cp = c * 4 + q4;
      int ch = cp ^ (row & 7);
      *(uint4*)&gC[cp * 8] = *(const uint4*)&SH[row * 128 + (ch << 3)];
    }
  }
}

// Transposed MFMA attention. One block per (b,h), 4 independent waves (qt = wave+4k).
// K a-frags staged once into LDS (lane-linear, conflict-free); V^T in swizzled LDS.
// S^T = K*Q^T (C-layout row=key, col=q). Softmax per column (2 shfls). P -> PV B-frag
// via quad-transpose shfl. O^T = V^T * P^T -> per-lane float4 stores.
__global__ __launch_bounds__(256) void k_attn_mfma(
    const ushort* __restrict__ Cb0, const float* __restrict__ biasF,
    float* __restrict__ out) {
  __shared__ __align__(16) ushort Vt[HDIM * 256];     // 32768 B, [d][key] swizzled
  __shared__ __align__(16) ushort Ka[NQT * 2 * 512];  // 26624 B, [t][half][lane][8]
  int bh = blockIdx.x;
  int b = bh / HEADS, h = bh - b * HEADS;
  int tid = threadIdx.x;
  int wave = tid >> 6, lane = tid & 63;
  int quad = lane >> 4, l16 = lane & 15;
  const ushort* Cb = Cb0 + (size_t)b * S_LEN * NCOLS;
  const int qoff = h * HDIM, koff = DMODEL + h * HDIM, voff = 2 * DMODEL + h * HDIM;

  { // zero Vt (key cols 197..255 must be 0.0)
    uint4 z4 = {0u, 0u, 0u, 0u};
    for (int i = tid; i < HDIM * 256 / 8; i += 256) ((uint4*)Vt)[i] = z4;
  }
  __syncthreads();
  for (int idx = tid; idx < S_LEN * 32; idx += 256) { // V -> V^T (swizzled scatter)
    int key = idx >> 5, dp = (idx & 31) * 2;
    unsigned int v = *(const unsigned int*)&Cb[(size_t)key * NCOLS + voff + dp];
    int ch = key >> 3, co = key & 7;
    Vt[dp * 256 + ((ch ^ (dp & 7)) << 3) + co] = (ushort)(v & 0xffffu);
    Vt[(dp + 1) * 256 + ((ch ^ ((dp + 1) & 7)) << 3) + co] = (ushort)(v >> 16);
  }
  // stage K a-frags: rows up to 207 read neighbor-batch data (finite; masked by bias)
  for (int th = wave; th < NQT * 2; th += 4) {
    int t = th >> 1, half = th & 1;
    short8 kf = *(const short8*)&Cb[(size_t)(t * 16 + l16) * NCOLS + koff + half * 32 + quad * 8];
    *(short8*)&Ka[th * 512 + lane * 8] = kf;
  }
  __syncthreads(); // last barrier; waves independent below

  for (int qt = wave; qt < NQT; qt += 4) {
    int q0 = qt * 16;
    int q = q0 + l16;
    short8 qb0 = *(const short8*)&Cb[(size_t)q * NCOLS + qoff + quad * 8];
    short8 qb1 = *(const short8*)&Cb[(size_t)q * NCOLS + qoff + 32 + quad * 8];
    const float* bF = biasF + ((size_t)((h * NQT + qt) * NQT) * 64 + lane) * 4;

    floatx4 sacc[NQT];
#pragma unroll
    for (int t = 0; t < NQT; ++t) {
      floatx4 cin = *(const floatx4*)&bF[t * 256]; // bias as MFMA C-init (mask baked in)
      short8 ka0 = *(const short8*)&Ka[(t * 2 + 0) * 512 + lane * 8];
      short8 ka1 = *(const short8*)&Ka[(t * 2 + 1) * 512 + lane * 8];
      floatx4 s1 = __builtin_amdgcn_mfma_f32_16x16x32_bf16(ka0, qb0, cin, 0, 0, 0);
      sacc[t] = __builtin_amdgcn_mfma_f32_16x16x32_bf16(ka1, qb1, s1, 0, 0, 0);
    }

    // softmax over keys (spread across quads+regs+tiles at fixed col q)
    float mx = -3e38f;
#pragma unroll
    for (int t = 0; t < NQT; ++t)
#pragma unroll
      for (int r = 0; r < 4; ++r) mx = fmaxf(mx, sacc[t][r]);
    mx = fmaxf(mx, __shfl_xor(mx, 16));
    mx = fmaxf(mx, __shfl_xor(mx, 32));
    float sum = 0.f;
    unsigned int pbf[NQT][2]; // packed bf16 pairs (rows 2r,2r+1), unnormalized
#pragma unroll
    for (int t = 0; t < NQT; ++t) {
      float e0 = __expf(sacc[t][0] - mx), e1 = __expf(sacc[t][1] - mx);
      float e2 = __expf(sacc[t][2] - mx), e3 = __expf(sacc[t][3] - mx);
      sum += (e0 + e1) + (e2 + e3);
      union { float f; unsigned int u; } a, bb, c, d;
      a.f = e0; bb.f = e1; c.f = e2; d.f = e3;
      pbf[t][0] = ((a.u + 0x8000u) >> 16) | ((bb.u + 0x8000u) & 0xffff0000u);
      pbf[t][1] = ((c.u + 0x8000u) >> 16) | ((d.u + 0x8000u) & 0xffff0000u);
    }
    sum += __shfl_xor(sum, 16);
    sum += __shfl_xor(sum, 32);
    float inv = 1.f / sum;

    // PV: O^T[d][q]; B-frag(P) lane(quad,l16) needs keys kk*32+quad*8+j of col q=l16
    floatx4 oacc[4];
    floatx4 zz = {0.f, 0.f, 0.f, 0.f};
#pragma unroll
    for (int dt = 0; dt < 4; ++dt) oacc[dt] = zz;
    int sel0 = ((quad & 1) * 2) * 16 + l16;
    int sel1 = sel0 + 16;
#pragma unroll
    for (int kk = 0; kk < 7; ++kk) {
      unsigned int u0 = 0, u1 = 0, u2 = 0, u3 = 0;
#pragma unroll
      for (int half = 0; half < 2; ++half) {
        int t = 2 * kk + half;
        if (t < NQT) {
          unsigned int v0 = __shfl((int)pbf[t][0], sel0);
          unsigned int v1 = __shfl((int)pbf[t][1], sel0);
          unsigned int v2 = __shfl((int)pbf[t][0], sel1);
          unsigned int v3 = __shfl((int)pbf[t][1], sel1);
          if ((quad >> 1) == half) { u0 = v0; u1 = v1; u2 = v2; u3 = v3; }
        }
      }
      union { uint4 u; short8 s; } pf;
      pf.u.x = u0; pf.u.y = u1; pf.u.z = u2; pf.u.w = u3;
#pragma unroll
      for (int dt = 0; dt < 4; ++dt) {
        int d = dt * 16 + l16;
        short8 vf = *(const short8*)&Vt[d * 256 + (((kk * 4 + quad) ^ (d & 7)) << 3)];
        oacc[dt] = __builtin_amdgcn_mfma_f32_16x16x32_bf16(vf, pf.s, oacc[dt], 0, 0, 0);
      }
    }

    // O^T C-layout: row=d=dt*16+quad*4+r, col=q=l16 -> per-lane float4 of consecutive d
    if (q < S_LEN) {
      float* og = out + ((size_t)b * S_LEN + q) * DMODEL + h * HDIM + quad * 4;
#pragma unroll
      for (int dt = 0; dt < 4; ++dt) {
        floatx4 o = oacc[dt];
        float4 st = make_float4(o[0] * inv, o[1] * inv, o[2] * inv, o[3] * inv);
        *(float4*)&og[dt * 16] = st;
      }
    }
  }
}

extern "C" void kernel_launch(void* const* d_in, const int* in_sizes, int n_in,
                              void* d_out, int out_size, void* d_ws, size_t ws_size,
                              hipStream_t stream) {
  const float* hs = (const float*)d_in[0];
  const float* wq = (const float*)d_in[1];
  const float* bq = (const float*)d_in[2];
  const float* wk = (const float*)d_in[3];
  const float* wv = (const float*)d_in[4];
  const float* bv = (const float*)d_in[5];
  const float* bt = (const float*)d_in[6];
  const int* ridx = (const int*)d_in[7];
  float* out = (float*)d_out;

  // workspace (~83.5 MB)
  ushort* hbf = (ushort*)d_ws;              // [12672][768] bf16
  ushort* wbf = hbf + (size_t)MPAD * KDIM;  // [2304][768] bf16
  ushort* Cb = wbf + (size_t)NCOLS * KDIM;  // [12672][2304] bf16 (QKV combined)
  float* biasF = (float*)(Cb + (size_t)MPAD * NCOLS); // [12][13][13][64][4] fp32

  k_prep<<<2048, 256, 0, stream>>>(hs, wq, wk, wv, bt, ridx, hbf, wbf, biasF);
  k_gemm_qkv<<<dim3(NTILE, MTILE), 256, 0, stream>>>(hbf, wbf, bq, bv, Cb);
  k_attn_mfma<<<BATCH * HEADS, 256, 0, stream>>>(Cb, biasF, out);
}